// Round 1
// baseline (33008.957 us; speedup 1.0000x reference)
//
#include <hip/hip_runtime.h>
#include <hip/hip_cooperative_groups.h>

namespace cg = cooperative_groups;

#define HDIM 2048   // LSTM_DIM
#define G4   8192   // 4*HDIM
#define NB   64     // BATCH
#define NT   512    // MAX_STEPS
#define MEL  512
#define KIN  512    // INPUT_SIZE

typedef __attribute__((ext_vector_type(8))) short short8;
typedef __attribute__((ext_vector_type(4))) float f32x4;

__device__ __forceinline__ unsigned short f2bf(float f){
  union { float f; unsigned u; } v; v.f = f;
  return (unsigned short)((v.u + 0x7fffu + ((v.u >> 16) & 1u)) >> 16);
}
__device__ __forceinline__ float sigm(float x){ return 1.f / (1.f + __expf(-x)); }
__device__ __forceinline__ float tanhfast(float x){ return 1.f - 2.f / (__expf(2.f * x) + 1.f); }

// ---------------- fp32 -> bf16 convert ----------------
__global__ void convert_kernel(const float* __restrict__ src, unsigned short* __restrict__ dst, int n4){
  int stride = gridDim.x * blockDim.x;
  for (int i = blockIdx.x * blockDim.x + threadIdx.x; i < n4; i += stride){
    const float4 v = *(const float4*)(src + (size_t)i * 4);
    uint2 pk;
    pk.x = (unsigned)f2bf(v.x) | ((unsigned)f2bf(v.y) << 16);
    pk.y = (unsigned)f2bf(v.z) | ((unsigned)f2bf(v.w) << 16);
    *(uint2*)(dst + (size_t)i * 4) = pk;
  }
}

// ---------------- b_eff = b_ih + b_hh + W_ih @ b_out ; bias0 = b_ih + b_hh ----------------
__global__ void beff_kernel(const float* __restrict__ W_ih, const float* __restrict__ b_ih,
                            const float* __restrict__ b_hh, const float* __restrict__ b_out,
                            float* __restrict__ b_eff, float* __restrict__ bias0){
  int r = blockIdx.x;
  int lane = threadIdx.x;  // 64 threads = 1 wave
  float acc = 0.f;
  for (int k = lane; k < KIN; k += 64) acc += W_ih[(size_t)r * KIN + k] * b_out[k];
  #pragma unroll
  for (int off = 32; off > 0; off >>= 1) acc += __shfl_down(acc, off, 64);
  if (lane == 0){
    float bb = b_ih[r] + b_hh[r];
    bias0[r] = bb;
    b_eff[r] = bb + acc;
  }
}

// ---------------- W_eff = bf16( W_hh + W_ih @ W_out )  [8192 x 2048], K=512 ----------------
__global__ __launch_bounds__(256) void weff_gemm(const float* __restrict__ W_ih, const float* __restrict__ W_out,
                                                 const float* __restrict__ W_hh, unsigned short* __restrict__ Weff){
  __shared__ __align__(16) float As[32][68];  // [k][m]
  __shared__ __align__(16) float Bs[32][68];  // [k][n]
  const int bn = blockIdx.x * 64;
  const int bm = blockIdx.y * 64;
  const int t = threadIdx.x;
  const int tx = t & 15, ty = t >> 4;
  float acc[4][4] = {};
  for (int k0 = 0; k0 < KIN; k0 += 32){
    #pragma unroll
    for (int i = 0; i < 2; i++){
      int f = t + i * 256;
      int row = f >> 3, c4 = (f & 7) * 4;
      const float4 v = *(const float4*)(W_ih + (size_t)(bm + row) * KIN + k0 + c4);
      As[c4 + 0][row] = v.x; As[c4 + 1][row] = v.y; As[c4 + 2][row] = v.z; As[c4 + 3][row] = v.w;
    }
    #pragma unroll
    for (int i = 0; i < 2; i++){
      int f = t + i * 256;
      int kr = f >> 4, c4 = (f & 15) * 4;
      *(float4*)&Bs[kr][c4] = *(const float4*)(W_out + (size_t)(k0 + kr) * HDIM + bn + c4);
    }
    __syncthreads();
    #pragma unroll
    for (int kk = 0; kk < 32; kk++){
      const float4 av = *(const float4*)&As[kk][ty * 4];
      const float4 bv = *(const float4*)&Bs[kk][tx * 4];
      const float ar[4] = {av.x, av.y, av.z, av.w};
      const float br[4] = {bv.x, bv.y, bv.z, bv.w};
      #pragma unroll
      for (int i = 0; i < 4; i++)
        #pragma unroll
        for (int j = 0; j < 4; j++)
          acc[i][j] += ar[i] * br[j];
    }
    __syncthreads();
  }
  #pragma unroll
  for (int i = 0; i < 4; i++){
    const size_t row = (size_t)bm + ty * 4 + i;
    const float4 wh = *(const float4*)(W_hh + row * HDIM + bn + tx * 4);
    uint2 pk;
    pk.x = (unsigned)f2bf(acc[i][0] + wh.x) | ((unsigned)f2bf(acc[i][1] + wh.y) << 16);
    pk.y = (unsigned)f2bf(acc[i][2] + wh.z) | ((unsigned)f2bf(acc[i][3] + wh.w) << 16);
    *(uint2*)(Weff + row * HDIM + bn + tx * 4) = pk;
  }
}

// ---------------- persistent cooperative decoder ----------------
// 256 WGs x 256 thr. WG w owns h-columns j in [8w, 8w+8): LDS rows 0..31 = gate rows
// (r = g*8 + jl -> global row g*2048 + 8w + jl), rows 32..33 = W_out rows 2w, 2w+1.
// Each wave = one 16-batch tile; 3 MFMA tiles (rows 0-15, 16-31, 32-47[y, rest garbage]).
#define LDSW 139264            // 34 rows * 2048 * 2B
#define LDSX (LDSW + 8192)     // + exchange: 4 waves * 32*16 f32

__global__ void __launch_bounds__(256, 1) decoder_coop(
    const unsigned short* __restrict__ Whh_b,
    const unsigned short* __restrict__ Weff_b,
    const unsigned short* __restrict__ Wout_b,
    const float* __restrict__ b_eff,
    const float* __restrict__ bias0,
    const float* __restrict__ c0,
    const float* __restrict__ b_out,
    unsigned short* __restrict__ hbuf,   // [2][64][2048] bf16; hbuf[0] pre-filled with bf16(h0)
    float* __restrict__ out)             // [64][512][512]
{
  extern __shared__ char smem[];
  cg::grid_group grid = cg::this_grid();
  const int w    = blockIdx.x;
  const int tid  = threadIdx.x;
  const int wave = tid >> 6;
  const int lane = tid & 63;
  const int bcol = lane & 15;          // batch col within tile / A row within tile
  const int q    = lane >> 4;          // k-block 0..3
  const int brow = wave * 16 + bcol;   // batch index

  const int r0 = bcol, r1 = 16 + bcol;
  int r2t = 32 + bcol; if (r2t > 33) r2t = 33;   // clamp: rows 34..47 are don't-care
  const int r2 = r2t;
  const int s0 = r0 & 7, s1 = r1 & 7, s2 = r2 & 7;

  // ---- initial LDS fill: gate rows from W_hh (step 0), y rows from W_out ----
  {
    const int r = tid >> 3;            // 0..31
    const int u0 = tid & 7;
    const int g = r >> 3, jl = r & 7;
    const unsigned short* src = Whh_b + ((size_t)(g * HDIM + w * 8 + jl)) * HDIM;
    char* dstrow = smem + r * 4096;
    const int sw = r & 7;
    #pragma unroll 4
    for (int i = 0; i < 32; i++){
      int u = u0 + i * 8;
      *(int4*)(dstrow + ((u ^ sw) << 4)) = *(const int4*)(src + (size_t)u * 8);
    }
  }
  if (tid < 16){
    const int rr = 32 + (tid & 1);
    const int m  = w * 2 + (tid & 1);
    const unsigned short* src = Wout_b + (size_t)m * HDIM;
    char* dstrow = smem + rr * 4096;
    const int sw = rr & 7;
    for (int i = 0; i < 32; i++){
      int u = (tid >> 1) + i * 8;
      *(int4*)(dstrow + ((u ^ sw) << 4)) = *(const int4*)(src + (size_t)u * 8);
    }
  }
  __syncthreads();

  // ---- per-lane constants ----
  const int jg0 = w * 8 + 2 * q;       // this lane's j pair base (global column index)
  const float be_i0 = b_eff[jg0],            be_i1 = b_eff[jg0 + 1];
  const float be_f0 = b_eff[HDIM + jg0],     be_f1 = b_eff[HDIM + jg0 + 1];
  const float be_g0 = b_eff[2 * HDIM + jg0], be_g1 = b_eff[2 * HDIM + jg0 + 1];
  const float be_o0 = b_eff[3 * HDIM + jg0], be_o1 = b_eff[3 * HDIM + jg0 + 1];
  const float byo0 = b_out[2 * w], byo1 = b_out[2 * w + 1];
  float cst0 = 0.f, cst1 = 0.f;        // c-state for the 2 owned (j,b) pairs
  float* ex = (float*)(smem + LDSW) + wave * 512;

  for (int t = 0; t < NT; t++){
    if (t == 1){
      // swap gate rows to W_eff (after step-0 grid sync)
      const int r = tid >> 3;
      const int u0 = tid & 7;
      const int g = r >> 3, jl = r & 7;
      const unsigned short* src = Weff_b + ((size_t)(g * HDIM + w * 8 + jl)) * HDIM;
      char* dstrow = smem + r * 4096;
      const int sw = r & 7;
      #pragma unroll 4
      for (int i = 0; i < 32; i++){
        int u = u0 + i * 8;
        *(int4*)(dstrow + ((u ^ sw) << 4)) = *(const int4*)(src + (size_t)u * 8);
      }
      __syncthreads();
    }
    const unsigned short* hsrc = hbuf + (size_t)(t & 1) * NB * HDIM;
    const unsigned short* hs = hsrc + (size_t)brow * HDIM + q * 8;

    f32x4 acc0 = {0.f,0.f,0.f,0.f}, acc1 = {0.f,0.f,0.f,0.f}, acc2 = {0.f,0.f,0.f,0.f};
    #pragma unroll 4
    for (int kk = 0; kk < HDIM / 32; kk++){
      const short8 bv = *(const short8*)(hs + kk * 32);
      const int un = kk * 4 + q;
      const short8 a0 = *(const short8*)(smem + r0 * 4096 + ((un ^ s0) << 4));
      const short8 a1 = *(const short8*)(smem + r1 * 4096 + ((un ^ s1) << 4));
      const short8 a2 = *(const short8*)(smem + r2 * 4096 + ((un ^ s2) << 4));
      acc0 = __builtin_amdgcn_mfma_f32_16x16x32_bf16(a0, bv, acc0, 0, 0, 0);
      acc1 = __builtin_amdgcn_mfma_f32_16x16x32_bf16(a1, bv, acc1, 0, 0, 0);
      acc2 = __builtin_amdgcn_mfma_f32_16x16x32_bf16(a2, bv, acc2, 0, 0, 0);
    }

    // ---- gate exchange within wave (per-wave LDS region) ----
    #pragma unroll
    for (int e = 0; e < 4; e++){
      ex[(q * 4 + e) * 16 + bcol]        = acc0[e];   // rows 0..15: i(jl 0-7), f(jl 0-7)
      ex[(16 + q * 4 + e) * 16 + bcol]   = acc1[e];   // rows 16..31: g, o
    }
    __syncthreads();
    const int jl0 = 2 * q;
    const float ai0 = ex[(jl0 + 0)  * 16 + bcol], ai1 = ex[(jl0 + 1)  * 16 + bcol];
    const float af0 = ex[(jl0 + 8)  * 16 + bcol], af1 = ex[(jl0 + 9)  * 16 + bcol];
    const float ag0 = ex[(jl0 + 16) * 16 + bcol], ag1 = ex[(jl0 + 17) * 16 + bcol];
    const float ao0 = ex[(jl0 + 24) * 16 + bcol], ao1 = ex[(jl0 + 25) * 16 + bcol];

    float bi0, bi1, bf0, bf1, bg0, bg1, bo0, bo1;
    if (t == 0){
      bi0 = bias0[jg0];            bi1 = bias0[jg0 + 1];
      bf0 = bias0[HDIM + jg0];     bf1 = bias0[HDIM + jg0 + 1];
      bg0 = bias0[2 * HDIM + jg0]; bg1 = bias0[2 * HDIM + jg0 + 1];
      bo0 = bias0[3 * HDIM + jg0]; bo1 = bias0[3 * HDIM + jg0 + 1];
      cst0 = c0[(size_t)brow * HDIM + jg0];
      cst1 = c0[(size_t)brow * HDIM + jg0 + 1];
    } else {
      bi0 = be_i0; bi1 = be_i1; bf0 = be_f0; bf1 = be_f1;
      bg0 = be_g0; bg1 = be_g1; bo0 = be_o0; bo1 = be_o1;
    }

    const float gi0 = sigm(ai0 + bi0), gf0 = sigm(af0 + bf0);
    const float gg0 = tanhfast(ag0 + bg0), go0 = sigm(ao0 + bo0);
    const float cn0 = gf0 * cst0 + gi0 * gg0;
    const float hn0 = go0 * tanhfast(cn0);
    const float gi1 = sigm(ai1 + bi1), gf1 = sigm(af1 + bf1);
    const float gg1 = tanhfast(ag1 + bg1), go1 = sigm(ao1 + bo1);
    const float cn1 = gf1 * cst1 + gi1 * gg1;
    const float hn1 = go1 * tanhfast(cn1);
    cst0 = cn0; cst1 = cn1;

    unsigned short* hdst = hbuf + (size_t)((t + 1) & 1) * NB * HDIM;
    *(unsigned*)(hdst + (size_t)brow * HDIM + jg0) =
        (unsigned)f2bf(hn0) | ((unsigned)f2bf(hn1) << 16);

    if (t >= 1 && q == 0){
      float2 yv; yv.x = acc2[0] + byo0; yv.y = acc2[1] + byo1;
      *(float2*)(out + ((size_t)brow * NT + (t - 1)) * MEL + 2 * w) = yv;
    }
    __threadfence();
    grid.sync();
  }

  // ---- final output frame: y_511 = h_512 @ W_out^T + b_out, h_512 in hbuf[0] ----
  {
    const unsigned short* hs = hbuf + (size_t)brow * HDIM + q * 8;
    f32x4 acc = {0.f,0.f,0.f,0.f};
    #pragma unroll 4
    for (int kk = 0; kk < HDIM / 32; kk++){
      const short8 bv = *(const short8*)(hs + kk * 32);
      const int un = kk * 4 + q;
      const short8 a2 = *(const short8*)(smem + r2 * 4096 + ((un ^ s2) << 4));
      acc = __builtin_amdgcn_mfma_f32_16x16x32_bf16(a2, bv, acc, 0, 0, 0);
    }
    if (q == 0){
      float2 yv; yv.x = acc[0] + byo0; yv.y = acc[1] + byo1;
      *(float2*)(out + ((size_t)brow * NT + 511) * MEL + 2 * w) = yv;
    }
  }
}

extern "C" void kernel_launch(void* const* d_in, const int* in_sizes, int n_in,
                              void* d_out, int out_size, void* d_ws, size_t ws_size,
                              hipStream_t stream){
  (void)in_sizes; (void)n_in; (void)out_size; (void)ws_size;
  const float* h0    = (const float*)d_in[1];
  const float* c0    = (const float*)d_in[2];
  const float* W_ih  = (const float*)d_in[3];
  const float* W_hh  = (const float*)d_in[4];
  const float* b_ih  = (const float*)d_in[5];
  const float* b_hh  = (const float*)d_in[6];
  const float* W_out = (const float*)d_in[7];
  const float* b_out = (const float*)d_in[8];
  float* out = (float*)d_out;

  char* p = (char*)d_ws;
  unsigned short* weff_b = (unsigned short*)p; p += (size_t)G4 * HDIM * 2;   // 33.5 MB
  unsigned short* whh_b  = (unsigned short*)p; p += (size_t)G4 * HDIM * 2;   // 33.5 MB
  unsigned short* wout_b = (unsigned short*)p; p += (size_t)MEL * HDIM * 2;  // 2 MB
  float* beff  = (float*)p; p += (size_t)G4 * 4;
  float* bias0 = (float*)p; p += (size_t)G4 * 4;
  unsigned short* hbuf = (unsigned short*)p; p += (size_t)2 * NB * HDIM * 2; // 512 KB

  convert_kernel<<<2048, 256, 0, stream>>>(W_hh, whh_b, G4 * HDIM / 4);
  convert_kernel<<<256, 256, 0, stream>>>(W_out, wout_b, MEL * HDIM / 4);
  convert_kernel<<<64, 256, 0, stream>>>(h0, hbuf, NB * HDIM / 4);
  beff_kernel<<<G4, 64, 0, stream>>>(W_ih, b_ih, b_hh, b_out, beff, bias0);
  weff_gemm<<<dim3(HDIM / 64, G4 / 64), 256, 0, stream>>>(W_ih, W_out, W_hh, weff_b);

  hipFuncSetAttribute((const void*)decoder_coop, hipFuncAttributeMaxDynamicSharedMemorySize, LDSX);
  void* kargs[] = { (void*)&whh_b, (void*)&weff_b, (void*)&wout_b, (void*)&beff, (void*)&bias0,
                    (void*)&c0, (void*)&b_out, (void*)&hbuf, (void*)&out };
  hipLaunchCooperativeKernel((const void*)decoder_coop, dim3(256), dim3(256), kargs, LDSX, stream);
}

// Round 2
// 7547.493 us; speedup vs baseline: 4.3735x; 4.3735x over previous
//
#include <hip/hip_runtime.h>

#define HDIM 2048   // LSTM_DIM
#define G4   8192   // 4*HDIM
#define NB   64     // BATCH
#define NT   512    // MAX_STEPS
#define MEL  512
#define KIN  512    // INPUT_SIZE
#define NWG  256

typedef __attribute__((ext_vector_type(8))) short short8;
typedef __attribute__((ext_vector_type(4))) float f32x4;

__device__ __forceinline__ unsigned short f2bf(float f){
  union { float f; unsigned u; } v; v.f = f;
  return (unsigned short)((v.u + 0x7fffu + ((v.u >> 16) & 1u)) >> 16);
}
__device__ __forceinline__ float sigm(float x){ return 1.f / (1.f + __expf(-x)); }
__device__ __forceinline__ float tanhfast(float x){ return 1.f - 2.f / (__expf(2.f * x) + 1.f); }

// ---------------- fp32 -> bf16 convert ----------------
__global__ void convert_kernel(const float* __restrict__ src, unsigned short* __restrict__ dst, int n4){
  int stride = gridDim.x * blockDim.x;
  for (int i = blockIdx.x * blockDim.x + threadIdx.x; i < n4; i += stride){
    const float4 v = *(const float4*)(src + (size_t)i * 4);
    uint2 pk;
    pk.x = (unsigned)f2bf(v.x) | ((unsigned)f2bf(v.y) << 16);
    pk.y = (unsigned)f2bf(v.z) | ((unsigned)f2bf(v.w) << 16);
    *(uint2*)(dst + (size_t)i * 4) = pk;
  }
}

// ---------------- b_eff = b_ih + b_hh + W_ih @ b_out ; bias0 = b_ih + b_hh ----------------
__global__ void beff_kernel(const float* __restrict__ W_ih, const float* __restrict__ b_ih,
                            const float* __restrict__ b_hh, const float* __restrict__ b_out,
                            float* __restrict__ b_eff, float* __restrict__ bias0){
  int r = blockIdx.x;
  int lane = threadIdx.x;  // 64 threads = 1 wave
  float acc = 0.f;
  for (int k = lane; k < KIN; k += 64) acc += W_ih[(size_t)r * KIN + k] * b_out[k];
  #pragma unroll
  for (int off = 32; off > 0; off >>= 1) acc += __shfl_down(acc, off, 64);
  if (lane == 0){
    float bb = b_ih[r] + b_hh[r];
    bias0[r] = bb;
    b_eff[r] = bb + acc;
  }
}

// ---------------- W_eff = bf16( W_hh + W_ih @ W_out )  [8192 x 2048], K=512 ----------------
__global__ __launch_bounds__(256) void weff_gemm(const float* __restrict__ W_ih, const float* __restrict__ W_out,
                                                 const float* __restrict__ W_hh, unsigned short* __restrict__ Weff){
  __shared__ __align__(16) float As[32][68];  // [k][m]
  __shared__ __align__(16) float Bs[32][68];  // [k][n]
  const int bn = blockIdx.x * 64;
  const int bm = blockIdx.y * 64;
  const int t = threadIdx.x;
  const int tx = t & 15, ty = t >> 4;
  float acc[4][4] = {};
  for (int k0 = 0; k0 < KIN; k0 += 32){
    #pragma unroll
    for (int i = 0; i < 2; i++){
      int f = t + i * 256;
      int row = f >> 3, c4 = (f & 7) * 4;
      const float4 v = *(const float4*)(W_ih + (size_t)(bm + row) * KIN + k0 + c4);
      As[c4 + 0][row] = v.x; As[c4 + 1][row] = v.y; As[c4 + 2][row] = v.z; As[c4 + 3][row] = v.w;
    }
    #pragma unroll
    for (int i = 0; i < 2; i++){
      int f = t + i * 256;
      int kr = f >> 4, c4 = (f & 15) * 4;
      *(float4*)&Bs[kr][c4] = *(const float4*)(W_out + (size_t)(k0 + kr) * HDIM + bn + c4);
    }
    __syncthreads();
    #pragma unroll
    for (int kk = 0; kk < 32; kk++){
      const float4 av = *(const float4*)&As[kk][ty * 4];
      const float4 bv = *(const float4*)&Bs[kk][tx * 4];
      const float ar[4] = {av.x, av.y, av.z, av.w};
      const float br[4] = {bv.x, bv.y, bv.z, bv.w};
      #pragma unroll
      for (int i = 0; i < 4; i++)
        #pragma unroll
        for (int j = 0; j < 4; j++)
          acc[i][j] += ar[i] * br[j];
    }
    __syncthreads();
  }
  #pragma unroll
  for (int i = 0; i < 4; i++){
    const size_t row = (size_t)bm + ty * 4 + i;
    const float4 wh = *(const float4*)(W_hh + row * HDIM + bn + tx * 4);
    uint2 pk;
    pk.x = (unsigned)f2bf(acc[i][0] + wh.x) | ((unsigned)f2bf(acc[i][1] + wh.y) << 16);
    pk.y = (unsigned)f2bf(acc[i][2] + wh.z) | ((unsigned)f2bf(acc[i][3] + wh.w) << 16);
    *(uint2*)(Weff + row * HDIM + bn + tx * 4) = pk;
  }
}

// ---------------- lightweight global barrier ----------------
// Arrival: WG leader bypass-stores monotone step count to its own slot (no RMW).
// Wait: all 256 threads poll one slot each (coalesced agent loads), then barrier.
// h-data release: h stored with agent-scope bypass stores (at IC once vmcnt drains
// at the first __syncthreads) -> no buffer_wbl2 needed. Acquire: leader buffer_inv.
__device__ __forceinline__ void gbar(unsigned* __restrict__ slots, int w, int tid, unsigned tgt){
  __syncthreads();   // all waves' h bypass-stores drained (vmcnt 0) before arrival
  if (tid == 0)
    __hip_atomic_store(slots + w, tgt, __ATOMIC_RELAXED, __HIP_MEMORY_SCOPE_AGENT);
  while (__hip_atomic_load(slots + tid, __ATOMIC_RELAXED, __HIP_MEMORY_SCOPE_AGENT) < tgt) {}
  __syncthreads();   // every slot confirmed by some thread -> all 256 WGs arrived
  if (tid == 0) __builtin_amdgcn_fence(__ATOMIC_ACQUIRE, "agent");  // inv L1/L2
  __syncthreads();   // inv complete before any h load of next step
}

// ---------------- persistent decoder ----------------
// 256 WGs x 256 thr. WG w owns h-columns j in [8w, 8w+8): LDS rows 0..31 = gate rows
// (r = g*8 + jl -> global row g*2048 + 8w + jl), rows 32..33 = W_out rows 2w, 2w+1.
// Each wave = one 16-batch tile; 3 MFMA tiles (rows 0-15, 16-31, 32-47[y, rest garbage]).
#define LDSW 139264              // 34 rows * 2048 * 2B
#define EXW  544                 // exchange row-pitch floats: 32*17 per wave
#define LDSX (LDSW + 4 * EXW * 4)

__global__ void __launch_bounds__(256, 1) decoder_coop(
    const unsigned short* __restrict__ Whh_b,
    const unsigned short* __restrict__ Weff_b,
    const unsigned short* __restrict__ Wout_b,
    const float* __restrict__ b_eff,
    const float* __restrict__ bias0,
    const float* __restrict__ c0,
    const float* __restrict__ b_out,
    unsigned short* __restrict__ hbuf,   // [2][64][2048] bf16; hbuf[0] pre-filled with bf16(h0)
    unsigned* __restrict__ slots,        // [256] zeroed
    float* __restrict__ out)             // [64][512][512]
{
  extern __shared__ char smem[];
  const int w    = blockIdx.x;
  const int tid  = threadIdx.x;
  const int wave = tid >> 6;
  const int lane = tid & 63;
  const int bcol = lane & 15;          // batch col within tile / A row within tile
  const int q    = lane >> 4;          // k-block 0..3
  const int brow = wave * 16 + bcol;   // batch index

  const int r0 = bcol, r1 = 16 + bcol;
  int r2t = 32 + bcol; if (r2t > 33) r2t = 33;   // clamp: rows 34..47 are don't-care
  const int r2 = r2t;
  const int s0 = r0 & 7, s1 = r1 & 7, s2 = r2 & 7;

  // ---- initial LDS fill: gate rows from W_hh (step 0), y rows from W_out ----
  {
    const int r = tid >> 3;            // 0..31
    const int u0 = tid & 7;
    const int g = r >> 3, jl = r & 7;
    const unsigned short* src = Whh_b + ((size_t)(g * HDIM + w * 8 + jl)) * HDIM;
    char* dstrow = smem + r * 4096;
    const int sw = r & 7;
    #pragma unroll 4
    for (int i = 0; i < 32; i++){
      int u = u0 + i * 8;
      *(int4*)(dstrow + ((u ^ sw) << 4)) = *(const int4*)(src + (size_t)u * 8);
    }
  }
  if (tid < 16){
    const int rr = 32 + (tid & 1);
    const int m  = w * 2 + (tid & 1);
    const unsigned short* src = Wout_b + (size_t)m * HDIM;
    char* dstrow = smem + rr * 4096;
    const int sw = rr & 7;
    for (int i = 0; i < 32; i++){
      int u = (tid >> 1) + i * 8;
      *(int4*)(dstrow + ((u ^ sw) << 4)) = *(const int4*)(src + (size_t)u * 8);
    }
  }
  __syncthreads();

  // ---- per-lane constants ----
  const int jg0 = w * 8 + 2 * q;       // this lane's j pair base (global column index)
  const float be_i0 = b_eff[jg0],            be_i1 = b_eff[jg0 + 1];
  const float be_f0 = b_eff[HDIM + jg0],     be_f1 = b_eff[HDIM + jg0 + 1];
  const float be_g0 = b_eff[2 * HDIM + jg0], be_g1 = b_eff[2 * HDIM + jg0 + 1];
  const float be_o0 = b_eff[3 * HDIM + jg0], be_o1 = b_eff[3 * HDIM + jg0 + 1];
  const float byo0 = b_out[2 * w], byo1 = b_out[2 * w + 1];
  float cst0 = 0.f, cst1 = 0.f;        // c-state for the 2 owned (j,b) pairs
  float* ex = (float*)(smem + LDSW) + wave * EXW;

  for (int t = 0; t < NT; t++){
    if (t == 1){
      // swap gate rows to W_eff (after step-0 barrier)
      const int r = tid >> 3;
      const int u0 = tid & 7;
      const int g = r >> 3, jl = r & 7;
      const unsigned short* src = Weff_b + ((size_t)(g * HDIM + w * 8 + jl)) * HDIM;
      char* dstrow = smem + r * 4096;
      const int sw = r & 7;
      #pragma unroll 4
      for (int i = 0; i < 32; i++){
        int u = u0 + i * 8;
        *(int4*)(dstrow + ((u ^ sw) << 4)) = *(const int4*)(src + (size_t)u * 8);
      }
      __syncthreads();
    }
    const unsigned short* hsrc = hbuf + (size_t)(t & 1) * NB * HDIM;
    const unsigned short* hs = hsrc + (size_t)brow * HDIM + q * 8;

    f32x4 acc0 = {0.f,0.f,0.f,0.f}, acc1 = {0.f,0.f,0.f,0.f}, acc2 = {0.f,0.f,0.f,0.f};
    #pragma unroll 4
    for (int kk = 0; kk < HDIM / 32; kk++){
      const short8 bv = *(const short8*)(hs + kk * 32);
      const int un = kk * 4 + q;
      const short8 a0 = *(const short8*)(smem + r0 * 4096 + ((un ^ s0) << 4));
      const short8 a1 = *(const short8*)(smem + r1 * 4096 + ((un ^ s1) << 4));
      const short8 a2 = *(const short8*)(smem + r2 * 4096 + ((un ^ s2) << 4));
      acc0 = __builtin_amdgcn_mfma_f32_16x16x32_bf16(a0, bv, acc0, 0, 0, 0);
      acc1 = __builtin_amdgcn_mfma_f32_16x16x32_bf16(a1, bv, acc1, 0, 0, 0);
      acc2 = __builtin_amdgcn_mfma_f32_16x16x32_bf16(a2, bv, acc2, 0, 0, 0);
    }

    // ---- gate exchange within wave (per-wave LDS region; wave-local sync only) ----
    #pragma unroll
    for (int e = 0; e < 4; e++){
      ex[(q * 4 + e) * 17 + bcol]        = acc0[e];   // rows 0..15: i(jl 0-7), f(jl 0-7)
      ex[(16 + q * 4 + e) * 17 + bcol]   = acc1[e];   // rows 16..31: g, o
    }
    asm volatile("s_waitcnt lgkmcnt(0)" ::: "memory");
    const int jl0 = 2 * q;
    const float ai0 = ex[(jl0 + 0)  * 17 + bcol], ai1 = ex[(jl0 + 1)  * 17 + bcol];
    const float af0 = ex[(jl0 + 8)  * 17 + bcol], af1 = ex[(jl0 + 9)  * 17 + bcol];
    const float ag0 = ex[(jl0 + 16) * 17 + bcol], ag1 = ex[(jl0 + 17) * 17 + bcol];
    const float ao0 = ex[(jl0 + 24) * 17 + bcol], ao1 = ex[(jl0 + 25) * 17 + bcol];

    float bi0, bi1, bf0, bf1, bg0, bg1, bo0, bo1;
    if (t == 0){
      bi0 = bias0[jg0];            bi1 = bias0[jg0 + 1];
      bf0 = bias0[HDIM + jg0];     bf1 = bias0[HDIM + jg0 + 1];
      bg0 = bias0[2 * HDIM + jg0]; bg1 = bias0[2 * HDIM + jg0 + 1];
      bo0 = bias0[3 * HDIM + jg0]; bo1 = bias0[3 * HDIM + jg0 + 1];
      cst0 = c0[(size_t)brow * HDIM + jg0];
      cst1 = c0[(size_t)brow * HDIM + jg0 + 1];
    } else {
      bi0 = be_i0; bi1 = be_i1; bf0 = be_f0; bf1 = be_f1;
      bg0 = be_g0; bg1 = be_g1; bo0 = be_o0; bo1 = be_o1;
    }

    const float gi0 = sigm(ai0 + bi0), gf0 = sigm(af0 + bf0);
    const float gg0 = tanhfast(ag0 + bg0), go0 = sigm(ao0 + bo0);
    const float cn0 = gf0 * cst0 + gi0 * gg0;
    const float hn0 = go0 * tanhfast(cn0);
    const float gi1 = sigm(ai1 + bi1), gf1 = sigm(af1 + bf1);
    const float gg1 = tanhfast(ag1 + bg1), go1 = sigm(ao1 + bo1);
    const float cn1 = gf1 * cst1 + gi1 * gg1;
    const float hn1 = go1 * tanhfast(cn1);
    cst0 = cn0; cst1 = cn1;

    // h store: agent-scope bypass store -> lands at IC, no wbl2 fence needed
    unsigned short* hdst = hbuf + (size_t)((t + 1) & 1) * NB * HDIM;
    const unsigned hpk = (unsigned)f2bf(hn0) | ((unsigned)f2bf(hn1) << 16);
    __hip_atomic_store((unsigned*)(hdst + (size_t)brow * HDIM + jg0), hpk,
                       __ATOMIC_RELAXED, __HIP_MEMORY_SCOPE_AGENT);

    if (t >= 1 && q == 0){
      float2 yv; yv.x = acc2[0] + byo0; yv.y = acc2[1] + byo1;
      *(float2*)(out + ((size_t)brow * NT + (t - 1)) * MEL + 2 * w) = yv;
    }
    gbar(slots, w, tid, (unsigned)(t + 1));
  }

  // ---- final output frame: y_511 = h_512 @ W_out^T + b_out, h_512 in hbuf[0] ----
  {
    const unsigned short* hs = hbuf + (size_t)brow * HDIM + q * 8;
    f32x4 acc = {0.f,0.f,0.f,0.f};
    #pragma unroll 4
    for (int kk = 0; kk < HDIM / 32; kk++){
      const short8 bv = *(const short8*)(hs + kk * 32);
      const int un = kk * 4 + q;
      const short8 a2 = *(const short8*)(smem + r2 * 4096 + ((un ^ s2) << 4));
      acc = __builtin_amdgcn_mfma_f32_16x16x32_bf16(a2, bv, acc, 0, 0, 0);
    }
    if (q == 0){
      float2 yv; yv.x = acc[0] + byo0; yv.y = acc[1] + byo1;
      *(float2*)(out + ((size_t)brow * NT + 511) * MEL + 2 * w) = yv;
    }
  }
}

extern "C" void kernel_launch(void* const* d_in, const int* in_sizes, int n_in,
                              void* d_out, int out_size, void* d_ws, size_t ws_size,
                              hipStream_t stream){
  (void)in_sizes; (void)n_in; (void)out_size; (void)ws_size;
  const float* h0    = (const float*)d_in[1];
  const float* c0    = (const float*)d_in[2];
  const float* W_ih  = (const float*)d_in[3];
  const float* W_hh  = (const float*)d_in[4];
  const float* b_ih  = (const float*)d_in[5];
  const float* b_hh  = (const float*)d_in[6];
  const float* W_out = (const float*)d_in[7];
  const float* b_out = (const float*)d_in[8];
  float* out = (float*)d_out;

  char* p = (char*)d_ws;
  unsigned short* weff_b = (unsigned short*)p; p += (size_t)G4 * HDIM * 2;   // 33.5 MB
  unsigned short* whh_b  = (unsigned short*)p; p += (size_t)G4 * HDIM * 2;   // 33.5 MB
  unsigned short* wout_b = (unsigned short*)p; p += (size_t)MEL * HDIM * 2;  // 2 MB
  float* beff  = (float*)p; p += (size_t)G4 * 4;
  float* bias0 = (float*)p; p += (size_t)G4 * 4;
  unsigned short* hbuf = (unsigned short*)p; p += (size_t)2 * NB * HDIM * 2; // 512 KB
  unsigned* slots = (unsigned*)p; p += NWG * sizeof(unsigned);

  hipMemsetAsync(slots, 0, NWG * sizeof(unsigned), stream);
  convert_kernel<<<2048, 256, 0, stream>>>(W_hh, whh_b, G4 * HDIM / 4);
  convert_kernel<<<256, 256, 0, stream>>>(W_out, wout_b, MEL * HDIM / 4);
  convert_kernel<<<64, 256, 0, stream>>>(h0, hbuf, NB * HDIM / 4);
  beff_kernel<<<G4, 64, 0, stream>>>(W_ih, b_ih, b_hh, b_out, beff, bias0);
  weff_gemm<<<dim3(HDIM / 64, G4 / 64), 256, 0, stream>>>(W_ih, W_out, W_hh, weff_b);

  hipFuncSetAttribute((const void*)decoder_coop, hipFuncAttributeMaxDynamicSharedMemorySize, LDSX);
  void* kargs[] = { (void*)&whh_b, (void*)&weff_b, (void*)&wout_b, (void*)&beff, (void*)&bias0,
                    (void*)&c0, (void*)&b_out, (void*)&hbuf, (void*)&slots, (void*)&out };
  hipLaunchCooperativeKernel((const void*)decoder_coop, dim3(256), dim3(256), kargs, LDSX, stream);
}